// Round 2
// baseline (975.907 us; speedup 1.0000x reference)
//
#include <hip/hip_runtime.h>
#include <cfloat>
#include <stdint.h>

// Problem constants
#define NROWS   32768
#define NCODES  8192
#define KDIM    256
#define QOUT_OFFSET (NROWS * KDIM)

// Main-kernel tiling (32x32x16 MFMA)
#define BM      64              // rows per block
#define BN      256             // codes per block-tile (4 waves x 64)
#define NQ      4               // codebook quarters
#define CODES_Q (NCODES / NQ)   // 2048
#define THREADS 256             // 4 waves

// Panel geometry (per 128-code, 32-k panel, 32x32 B-fragment order)
// Within panel: byte = ((ctile32*2 + s16)*64 + lane)*16 + e*2
//   lane = ((k16>>3)<<5) | (code&31), e = k&7
#define BPAN 8192               // 128 codes * 32 k * 2 B, one split
#define BBUF (2 * BPAN)         // hi+lo 16384
#define ALDS_SPLIT 32768        // 64 rows * 256 k * 2 B per split
// LDS: 2 * 32768 = 65536 B -> 2 blocks/CU

typedef __bf16 bf16x4 __attribute__((ext_vector_type(4)));
typedef __bf16 bf16x8 __attribute__((ext_vector_type(8)));
typedef float  f32x16 __attribute__((ext_vector_type(16)));

// ---------------------------------------------------------------------------
// K1: codebook -> hi/lo bf16 panels in 32x32-MFMA-fragment order, + cnorm.
// Panel p = (code>>7)*8 + kc (kc = 32-k chunk).
// ---------------------------------------------------------------------------
__global__ void vq_panel_kernel(const float* __restrict__ cb,
                                char* __restrict__ cbP,
                                float* __restrict__ cnorm) {
    const int t    = threadIdx.x;
    const int row  = t >> 2;
    const int seg  = t & 3;
    const int code = blockIdx.x * 64 + row;
    const int cl   = code & 127;
    const int pt   = code >> 7;
    const float4* cb4 = (const float4*)cb;

    float ssq = 0.f;
    #pragma unroll
    for (int i = 0; i < 16; ++i) {
        int f = seg * 16 + i;            // float4 index in row, 0..63
        float4 v = cb4[(size_t)code * 64 + f];
        int k  = f * 4;
        int kc = k >> 5;                 // 32-k chunk
        int s  = (k >> 4) & 1;           // 16-k half within chunk
        int g  = (k >> 3) & 1;           // lane group (k bit 3)
        int e  = k & 7;                  // 0 or 4
        bf16x4 h, l;
        float xs[4] = {v.x, v.y, v.z, v.w};
        #pragma unroll
        for (int e2 = 0; e2 < 4; ++e2) {
            __bf16 hh = (__bf16)xs[e2];
            h[e2] = hh;
            l[e2] = (__bf16)(xs[e2] - (float)hh);
            ssq  = fmaf(xs[e2], xs[e2], ssq);
        }
        int lane = (g << 5) | (code & 31);
        char* base = cbP + (size_t)(pt * 8 + kc) * BBUF
                   + (((cl >> 5) * 2 + s) * 64 + lane) * 16 + e * 2;
        *(bf16x4*)base          = h;
        *(bf16x4*)(base + BPAN) = l;
    }
    ssq += __shfl_xor(ssq, 1, 64);
    ssq += __shfl_xor(ssq, 2, 64);
    if (seg == 0) cnorm[code] = ssq;
}

// ---------------------------------------------------------------------------
// K2: split-bf16 32x32x16 MFMA distances + per-quarter argmin partials.
// Barrier-free K-loop; 24 MFMAs/iter (vs 48 with 16x16x32) -> half the MFMA
// issue slots at a 15% higher FLOP/cycle ceiling. A fragments read via ONE
// VGPR address + 16-bit ds offsets; B loads 1-deep register-prefetched.
// ---------------------------------------------------------------------------
__global__ __launch_bounds__(THREADS, 2) void vq_main_kernel(
        const float* __restrict__ z, const char* __restrict__ cbP,
        const float* __restrict__ cnorm,
        float* __restrict__ partD, int* __restrict__ partI) {

    __shared__ __align__(16) char Alds[2 * ALDS_SPLIT];   // 65536 B

    const int t     = threadIdx.x;
    const int wave  = t >> 6;
    const int lane  = t & 63;
    const int l31   = lane & 31;
    const int q     = blockIdx.x >> 9;
    const int row0  = (blockIdx.x & 511) * BM;
    const int qcode = q * CODES_Q;
    const int qp16  = q * 16;              // global 128-code panel-group base
    const int wh    = wave >> 1;           // wave's panel (128-code) half
    const int wboff = (wave & 1) * 4096 + lane * 16;  // within-panel base

    const float4* z4 = (const float4*)z;

    f32x16 acc[2][2];
    float mv[32];
    int   mi[32];
    #pragma unroll
    for (int i = 0; i < 2; ++i)
        #pragma unroll
        for (int j = 0; j < 2; ++j)
            #pragma unroll
            for (int r = 0; r < 16; ++r)
                acc[i][j][r] = 0.f;
    #pragma unroll
    for (int s = 0; s < 32; ++s) { mv[s] = FLT_MAX; mi[s] = 0; }

    // ---- prologue: stage A (all 8 kc, hi+lo, 32x32 fragment order) ----
    // layout: offset = kc*4096 + i32*2048 + s16*1024 + lane*16
    {
        const int arow = t >> 2;
        const int aseg = t & 3;
        const int ai   = arow >> 5;
        const int al31 = arow & 31;
        #pragma unroll
        for (int p = 0; p < 8; ++p) {
            float4 f0 = z4[(size_t)(row0 + arow) * 64 + aseg * 16 + 2 * p];
            float4 f1 = z4[(size_t)(row0 + arow) * 64 + aseg * 16 + 2 * p + 1];
            float xs[8] = {f0.x, f0.y, f0.z, f0.w, f1.x, f1.y, f1.z, f1.w};
            bf16x8 hv, lv;
            #pragma unroll
            for (int e = 0; e < 8; ++e) {
                __bf16 hh = (__bf16)xs[e];
                hv[e] = hh;
                lv[e] = (__bf16)(xs[e] - (float)hh);
            }
            // k = aseg*64 + p*8
            int kc = aseg * 2 + (p >> 2);
            int s  = (p >> 1) & 1;
            int g  = p & 1;
            int slot = kc * 4096 + ai * 2048 + s * 1024 + ((g << 5) | al31) * 16;
            *(bf16x8*)(Alds + slot)              = hv;
            *(bf16x8*)(Alds + ALDS_SPLIT + slot) = lv;
        }
    }

    // ---- prologue: B fragments for (ct=0, kc=0) ----
    const char* pct = cbP + (size_t)(qp16 + wh) * 8 * BBUF + wboff;
    bf16x8 B0h[4], B0l[4], B1h[4], B1l[4];   // [j*2+s]
    #pragma unroll
    for (int js = 0; js < 4; ++js) {
        B0h[js] = *(const bf16x8*)(pct + js * 1024);
        B0l[js] = *(const bf16x8*)(pct + BPAN + js * 1024);
    }

    __syncthreads();   // A ready; the ONLY barrier before the reduction

    const char* ab = (const char*)Alds + (lane << 4);
    float cnj[2];

#define VQ_KC(KC, NOFF, PREF, CBH, CBL, NBH, NBL)                             \
    {                                                                         \
        if (PREF) {                                                           \
            const char* pn  = pct + (size_t)(NOFF) * BBUF;                    \
            _Pragma("unroll")                                                 \
            for (int js = 0; js < 4; ++js) {                                  \
                NBH[js] = *(const bf16x8*)(pn + js * 1024);                   \
                NBL[js] = *(const bf16x8*)(pn + BPAN + js * 1024);            \
            }                                                                 \
        }                                                                     \
        bf16x8 ah[4], al[4];                                                  \
        _Pragma("unroll")                                                     \
        for (int is = 0; is < 4; ++is) {                                      \
            ah[is] = *(const bf16x8*)(ab + (KC) * 4096 + is * 1024);          \
            al[is] = *(const bf16x8*)(ab + ALDS_SPLIT + (KC) * 4096 + is * 1024); \
        }                                                                     \
        __builtin_amdgcn_s_setprio(1);                                        \
        _Pragma("unroll")                                                     \
        for (int i = 0; i < 2; ++i)                                           \
            _Pragma("unroll")                                                 \
            for (int j = 0; j < 2; ++j)                                       \
                _Pragma("unroll")                                             \
                for (int s = 0; s < 2; ++s)                                   \
                    acc[i][j] = __builtin_amdgcn_mfma_f32_32x32x16_bf16(      \
                        ah[i * 2 + s], CBH[j * 2 + s], acc[i][j], 0, 0, 0);   \
        _Pragma("unroll")                                                     \
        for (int i = 0; i < 2; ++i)                                           \
            _Pragma("unroll")                                                 \
            for (int j = 0; j < 2; ++j)                                       \
                _Pragma("unroll")                                             \
                for (int s = 0; s < 2; ++s)                                   \
                    acc[i][j] = __builtin_amdgcn_mfma_f32_32x32x16_bf16(      \
                        ah[i * 2 + s], CBL[j * 2 + s], acc[i][j], 0, 0, 0);   \
        _Pragma("unroll")                                                     \
        for (int i = 0; i < 2; ++i)                                           \
            _Pragma("unroll")                                                 \
            for (int j = 0; j < 2; ++j)                                       \
                _Pragma("unroll")                                             \
                for (int s = 0; s < 2; ++s)                                   \
                    acc[i][j] = __builtin_amdgcn_mfma_f32_32x32x16_bf16(      \
                        al[i * 2 + s], CBH[j * 2 + s], acc[i][j], 0, 0, 0);   \
        __builtin_amdgcn_s_setprio(0);                                        \
    }

    for (int ct = 0; ct < 8; ++ct) {
        #pragma unroll
        for (int j = 0; j < 2; ++j)
            cnj[j] = cnorm[qcode + ct * 256 + wave * 64 + j * 32 + l31];
        const bool morect = (ct < 7);
        VQ_KC(0, 1,  true,   B0h, B0l, B1h, B1l)
        VQ_KC(1, 2,  true,   B1h, B1l, B0h, B0l)
        VQ_KC(2, 3,  true,   B0h, B0l, B1h, B1l)
        VQ_KC(3, 4,  true,   B1h, B1l, B0h, B0l)
        VQ_KC(4, 5,  true,   B0h, B0l, B1h, B1l)
        VQ_KC(5, 6,  true,   B1h, B1l, B0h, B0l)
        VQ_KC(6, 7,  true,   B0h, B0l, B1h, B1l)
        VQ_KC(7, 16, morect, B1h, B1l, B0h, B0l)

        // ---- epilogue: distances + argmin update, zero acc ----
        #pragma unroll
        for (int j = 0; j < 2; ++j) {
            const float cn  = cnj[j];
            const int  code = qcode + ct * 256 + wave * 64 + j * 32 + l31;
            #pragma unroll
            for (int i = 0; i < 2; ++i)
                #pragma unroll
                for (int r = 0; r < 16; ++r) {
                    float d = fmaf(-2.f, acc[i][j][r], cn);
                    const int sl = i * 16 + r;
                    if (d < mv[sl]) { mv[sl] = d; mi[sl] = code; }
                }
        }
        #pragma unroll
        for (int i = 0; i < 2; ++i)
            #pragma unroll
            for (int j = 0; j < 2; ++j)
                #pragma unroll
                for (int r = 0; r < 16; ++r)
                    acc[i][j][r] = 0.f;

        pct += (size_t)16 * BBUF;
    }
#undef VQ_KC

    // ---- reduction: 32-lane butterfly over codes (groups intact) ----
    #pragma unroll
    for (int sl = 0; sl < 32; ++sl) {
        #pragma unroll
        for (int m = 1; m <= 16; m <<= 1) {
            float ov = __shfl_xor(mv[sl], m, 64);
            int   oi = __shfl_xor(mi[sl], m, 64);
            if (ov < mv[sl] || (ov == mv[sl] && oi < mi[sl])) { mv[sl] = ov; mi[sl] = oi; }
        }
    }
    __syncthreads();
    float* redV = (float*)Alds;                 // [4 wave][64 rows]
    int*   redI = (int*)(Alds + 4 * BM * 4);
    if (l31 == 0) {
        const int hi = lane >> 5;
        #pragma unroll
        for (int i = 0; i < 2; ++i)
            #pragma unroll
            for (int r = 0; r < 16; ++r) {
                int rowl = i * 32 + (r & 3) + 8 * (r >> 2) + 4 * hi;
                redV[wave * BM + rowl] = mv[i * 16 + r];
                redI[wave * BM + rowl] = mi[i * 16 + r];
            }
    }
    __syncthreads();
    if (t < BM) {
        float bv = redV[t];
        int   bi = redI[t];
        #pragma unroll
        for (int w = 1; w < 4; ++w) {
            float v  = redV[w * BM + t];
            int   id = redI[w * BM + t];
            if (v < bv || (v == bv && id < bi)) { bv = v; bi = id; }
        }
        partD[(size_t)q * NROWS + row0 + t] = bv;
        partI[(size_t)q * NROWS + row0 + t] = bi;
    }
}

// ---------------------------------------------------------------------------
// K3: merge 4 quarter-partials per row -> final index (ascending q keeps
// numpy first-min tie-breaking).
// ---------------------------------------------------------------------------
__global__ void vq_merge_kernel(const float* __restrict__ partD,
                                const int* __restrict__ partI,
                                float* __restrict__ idx_out) {
    const int row = blockIdx.x * 256 + threadIdx.x;
    float bv = partD[row];
    int   bi = partI[row];
    #pragma unroll
    for (int q = 1; q < NQ; ++q) {
        float v  = partD[(size_t)q * NROWS + row];
        int   id = partI[(size_t)q * NROWS + row];
        if (v < bv || (v == bv && id < bi)) { bv = v; bi = id; }
    }
    idx_out[row] = (float)bi;
}

// ---------------------------------------------------------------------------
// K4: gather codebook rows into quantized output (bit-exact fp32).
// ---------------------------------------------------------------------------
__global__ void vq_gather_kernel(const float* __restrict__ cb,
                                 const float* __restrict__ idx_f,
                                 float* __restrict__ quant) {
    const int t   = threadIdx.x;
    const int row = blockIdx.x * 64 + (t >> 2);
    const int seg = t & 3;
    const int best = (int)idx_f[row];
    const float4* src = (const float4*)cb + (size_t)best * (KDIM / 4);
    float4* dst = (float4*)quant + (size_t)row * (KDIM / 4);
    #pragma unroll
    for (int i = 0; i < 16; ++i)
        dst[seg * 16 + i] = src[seg * 16 + i];
}

// ---------------------------------------------------------------------------
extern "C" void kernel_launch(void* const* d_in, const int* in_sizes, int n_in,
                              void* d_out, int out_size, void* d_ws, size_t ws_size,
                              hipStream_t stream) {
    const float* z  = (const float*)d_in[0];
    const float* cb = (const float*)d_in[1];
    float* quant   = (float*)d_out;
    float* idx_out = (float*)d_out + QOUT_OFFSET;
    float* cnorm   = (float*)d_ws;                 // 32 KB scratch
    char*  cbP     = (char*)d_out;                 // 8 MB panels in quant region
    float* partD   = (float*)((char*)d_out + 8 * 1024 * 1024);   // 512 KB
    int*   partI   = (int*)((char*)d_out + 8 * 1024 * 1024 + NQ * NROWS * 4);
    // panels+partials live inside the 32 MB quant region; K4 overwrites last

    vq_panel_kernel<<<NCODES / 64, 256, 0, stream>>>(cb, cbP, cnorm);
    vq_main_kernel<<<NQ * (NROWS / BM), THREADS, 0, stream>>>(z, cbP, cnorm, partD, partI);
    vq_merge_kernel<<<NROWS / 256, 256, 0, stream>>>(partD, partI, idx_out);
    vq_gather_kernel<<<NROWS / 64, 256, 0, stream>>>(cb, idx_out, quant);
}

// Round 3
// 538.348 us; speedup vs baseline: 1.8128x; 1.8128x over previous
//
#include <hip/hip_runtime.h>
#include <cfloat>
#include <stdint.h>

// Problem constants
#define NROWS   32768
#define NCODES  8192
#define KDIM    256
#define QOUT_OFFSET (NROWS * KDIM)

// Main-kernel tiling (32x32x16 MFMA)
#define BM      64              // rows per block
#define NQ      4               // codebook quarters
#define CODES_Q (NCODES / NQ)   // 2048
#define NCT     16              // 128-code tiles per quarter
#define THREADS 256             // 4 waves: wave = rh + 2*ch (rh=row half, ch=code half)

// Panel geometry (per 128-code, 32-k panel, 32x32 B-fragment order)
// Within panel: byte = ((ctile32*2 + s16)*64 + lane)*16 + e*2
//   lane = ((k16>>3)<<5) | (code&31), e = k&7
#define BPAN 8192               // 128 codes * 32 k * 2 B, one split
#define BBUF (2 * BPAN)         // hi+lo 16384
#define ALDS_SPLIT 32768        // 64 rows * 256 k * 2 B per split
// LDS: 2 * 32768 = 65536 B -> 2 blocks/CU

typedef __bf16 bf16x4 __attribute__((ext_vector_type(4)));
typedef __bf16 bf16x8 __attribute__((ext_vector_type(8)));
typedef float  f32x16 __attribute__((ext_vector_type(16)));

// ---------------------------------------------------------------------------
// K1: codebook -> hi/lo bf16 panels in 32x32-MFMA-fragment order, + cnorm.
// (unchanged from the refcheck-clean R2 version)
// ---------------------------------------------------------------------------
__global__ void vq_panel_kernel(const float* __restrict__ cb,
                                char* __restrict__ cbP,
                                float* __restrict__ cnorm) {
    const int t    = threadIdx.x;
    const int row  = t >> 2;
    const int seg  = t & 3;
    const int code = blockIdx.x * 64 + row;
    const int cl   = code & 127;
    const int pt   = code >> 7;
    const float4* cb4 = (const float4*)cb;

    float ssq = 0.f;
    #pragma unroll
    for (int i = 0; i < 16; ++i) {
        int f = seg * 16 + i;            // float4 index in row, 0..63
        float4 v = cb4[(size_t)code * 64 + f];
        int k  = f * 4;
        int kc = k >> 5;                 // 32-k chunk
        int s  = (k >> 4) & 1;           // 16-k half within chunk
        int g  = (k >> 3) & 1;           // lane group (k bit 3)
        int e  = k & 7;                  // 0 or 4
        bf16x4 h, l;
        float xs[4] = {v.x, v.y, v.z, v.w};
        #pragma unroll
        for (int e2 = 0; e2 < 4; ++e2) {
            __bf16 hh = (__bf16)xs[e2];
            h[e2] = hh;
            l[e2] = (__bf16)(xs[e2] - (float)hh);
            ssq  = fmaf(xs[e2], xs[e2], ssq);
        }
        int lane = (g << 5) | (code & 31);
        char* base = cbP + (size_t)(pt * 8 + kc) * BBUF
                   + (((cl >> 5) * 2 + s) * 64 + lane) * 16 + e * 2;
        *(bf16x4*)base          = h;
        *(bf16x4*)(base + BPAN) = l;
    }
    ssq += __shfl_xor(ssq, 1, 64);
    ssq += __shfl_xor(ssq, 2, 64);
    if (seg == 0) cnorm[code] = ssq;
}

// ---------------------------------------------------------------------------
// K2: split-bf16 32x32x16 MFMA distances + per-quarter argmin partials.
// Wave tile 32 rows x 64 codes (rh = wave&1 row half, ch = wave>>1 code
// half) -> per-wave live state ~175 regs, no spill (R2's 64x64 tile at this
// shape spilled 1.3 GB to scratch). 12 MFMAs/iter, 4 ds_read_b128/iter off
// one VGPR address + 16-bit offsets, B register-double-buffered with a
// linearly-advancing panel pointer.
// ---------------------------------------------------------------------------
__global__ __launch_bounds__(THREADS, 2) void vq_main_kernel(
        const float* __restrict__ z, const char* __restrict__ cbP,
        const float* __restrict__ cnorm,
        float* __restrict__ partD, int* __restrict__ partI) {

    __shared__ __align__(16) char Alds[2 * ALDS_SPLIT];   // 65536 B

    const int t     = threadIdx.x;
    const int wave  = t >> 6;
    const int lane  = t & 63;
    const int l31   = lane & 31;
    const int hi    = lane >> 5;
    const int rh    = wave & 1;            // row half (rows rh*32 .. rh*32+31)
    const int ch    = wave >> 1;           // code half (codes ch*64 .. +63)
    const int q     = blockIdx.x >> 9;
    const int row0  = (blockIdx.x & 511) * BM;
    const int qcode = q * CODES_Q;

    const float4* z4 = (const float4*)z;

    f32x16 acc[2];                          // [j] two 32-code tiles
    float mv[16];
    int   mi[16];
    #pragma unroll
    for (int j = 0; j < 2; ++j)
        #pragma unroll
        for (int r = 0; r < 16; ++r)
            acc[j][r] = 0.f;
    #pragma unroll
    for (int r = 0; r < 16; ++r) { mv[r] = FLT_MAX; mi[r] = 0; }

    // ---- prologue: stage A (all 8 kc, hi+lo, 32x32 fragment order) ----
    // layout: offset = kc*4096 + i32*2048 + s16*1024 + lane*16
    {
        const int arow = t >> 2;
        const int aseg = t & 3;
        const int ai   = arow >> 5;
        const int al31 = arow & 31;
        #pragma unroll
        for (int p = 0; p < 8; ++p) {
            float4 f0 = z4[(size_t)(row0 + arow) * 64 + aseg * 16 + 2 * p];
            float4 f1 = z4[(size_t)(row0 + arow) * 64 + aseg * 16 + 2 * p + 1];
            float xs[8] = {f0.x, f0.y, f0.z, f0.w, f1.x, f1.y, f1.z, f1.w};
            bf16x8 hv, lv;
            #pragma unroll
            for (int e = 0; e < 8; ++e) {
                __bf16 hh = (__bf16)xs[e];
                hv[e] = hh;
                lv[e] = (__bf16)(xs[e] - (float)hh);
            }
            // k = aseg*64 + p*8
            int kc = aseg * 2 + (p >> 2);
            int s  = (p >> 1) & 1;
            int g  = p & 1;
            int slot = kc * 4096 + ai * 2048 + s * 1024 + ((g << 5) | al31) * 16;
            *(bf16x8*)(Alds + slot)              = hv;
            *(bf16x8*)(Alds + ALDS_SPLIT + slot) = lv;
        }
    }

    // ---- prologue: B fragments for panel 0 (ct=0, kc=0) ----
    // pq: quarter base + wave's within-panel offset (code half + lane)
    const char* pq = cbP + (size_t)q * 128 * BBUF + (ch << 12) + (lane << 4);
    bf16x8 B0h[4], B0l[4], B1h[4], B1l[4];   // [j*2+s]
    #pragma unroll
    for (int js = 0; js < 4; ++js) {
        B0h[js] = *(const bf16x8*)(pq + js * 1024);
        B0l[js] = *(const bf16x8*)(pq + BPAN + js * 1024);
    }

    __syncthreads();   // A ready; the ONLY barrier before the reduction

    // ---- prologue: A fragments for kc=0 ----
    const char* ab = (const char*)Alds + (rh << 11) + (lane << 4);
    bf16x8 A0h[2], A0l[2], A1h[2], A1l[2];   // [s]
    #pragma unroll
    for (int s = 0; s < 2; ++s) {
        A0h[s] = *(const bf16x8*)(ab + s * 1024);
        A0l[s] = *(const bf16x8*)(ab + ALDS_SPLIT + s * 1024);
    }

#define VQ_KC(KC, PB, CAH, CAL, NAH, NAL, CBH, CBL, NBH, NBL)                 \
    {                                                                         \
        const char* pn = (PB) + ((KC) + 1) * BBUF;                            \
        _Pragma("unroll")                                                     \
        for (int js = 0; js < 4; ++js) {                                      \
            NBH[js] = *(const bf16x8*)(pn + js * 1024);                       \
            NBL[js] = *(const bf16x8*)(pn + BPAN + js * 1024);                \
        }                                                                     \
        {                                                                     \
            const int kn = ((KC) + 1) & 7;                                    \
            _Pragma("unroll")                                                 \
            for (int s = 0; s < 2; ++s) {                                     \
                NAH[s] = *(const bf16x8*)(ab + kn * 4096 + s * 1024);         \
                NAL[s] = *(const bf16x8*)(ab + ALDS_SPLIT + kn * 4096 + s * 1024); \
            }                                                                 \
        }                                                                     \
        __builtin_amdgcn_s_setprio(1);                                        \
        _Pragma("unroll")                                                     \
        for (int s = 0; s < 2; ++s)                                           \
            _Pragma("unroll")                                                 \
            for (int j = 0; j < 2; ++j)                                       \
                acc[j] = __builtin_amdgcn_mfma_f32_32x32x16_bf16(             \
                    CAH[s], CBH[j * 2 + s], acc[j], 0, 0, 0);                 \
        _Pragma("unroll")                                                     \
        for (int s = 0; s < 2; ++s)                                           \
            _Pragma("unroll")                                                 \
            for (int j = 0; j < 2; ++j)                                       \
                acc[j] = __builtin_amdgcn_mfma_f32_32x32x16_bf16(             \
                    CAH[s], CBL[j * 2 + s], acc[j], 0, 0, 0);                 \
        _Pragma("unroll")                                                     \
        for (int s = 0; s < 2; ++s)                                           \
            _Pragma("unroll")                                                 \
            for (int j = 0; j < 2; ++j)                                       \
                acc[j] = __builtin_amdgcn_mfma_f32_32x32x16_bf16(             \
                    CAL[s], CBH[j * 2 + s], acc[j], 0, 0, 0);                 \
        __builtin_amdgcn_s_setprio(0);                                        \
    }

    for (int ct = 0; ct < NCT; ++ct) {
        const char* pct8 = pq + (size_t)ct * 8 * BBUF;
        const int  cbase = qcode + ct * 128 + ch * 64 + l31;
        const float cn0  = cnorm[cbase];
        const float cn1  = cnorm[cbase + 32];

        VQ_KC(0, pct8, A0h, A0l, A1h, A1l, B0h, B0l, B1h, B1l)
        VQ_KC(1, pct8, A1h, A1l, A0h, A0l, B1h, B1l, B0h, B0l)
        VQ_KC(2, pct8, A0h, A0l, A1h, A1l, B0h, B0l, B1h, B1l)
        VQ_KC(3, pct8, A1h, A1l, A0h, A0l, B1h, B1l, B0h, B0l)
        VQ_KC(4, pct8, A0h, A0l, A1h, A1l, B0h, B0l, B1h, B1l)
        VQ_KC(5, pct8, A1h, A1l, A0h, A0l, B1h, B1l, B0h, B0l)
        VQ_KC(6, pct8, A0h, A0l, A1h, A1l, B0h, B0l, B1h, B1l)
        VQ_KC(7, pct8, A1h, A1l, A0h, A0l, B1h, B1l, B0h, B0l)

        // ---- epilogue: distances + argmin update, zero acc ----
        // j=0 before j=1 keeps ascending-code order (first-min ties)
        #pragma unroll
        for (int j = 0; j < 2; ++j) {
            const float cn   = j ? cn1 : cn0;
            const int   code = cbase + j * 32;
            #pragma unroll
            for (int r = 0; r < 16; ++r) {
                float d = fmaf(-2.f, acc[j][r], cn);
                if (d < mv[r]) { mv[r] = d; mi[r] = code; }
            }
            #pragma unroll
            for (int r = 0; r < 16; ++r)
                acc[j][r] = 0.f;
        }
    }
#undef VQ_KC

    // ---- reduction: butterfly over 32 columns (l31), rows stay put ----
    #pragma unroll
    for (int r = 0; r < 16; ++r) {
        #pragma unroll
        for (int m = 1; m <= 16; m <<= 1) {
            float ov = __shfl_xor(mv[r], m, 64);
            int   oi = __shfl_xor(mi[r], m, 64);
            if (ov < mv[r] || (ov == mv[r] && oi < mi[r])) { mv[r] = ov; mi[r] = oi; }
        }
    }
    __syncthreads();   // all waves done with A data before LDS reuse
    float* redV = (float*)Alds;                 // [2 ch][64 rows]
    int*   redI = (int*)(Alds + 1024);
    if (l31 == 0) {
        #pragma unroll
        for (int r = 0; r < 16; ++r) {
            int rowl = rh * 32 + (r & 3) + 8 * (r >> 2) + 4 * hi;
            redV[ch * 64 + rowl] = mv[r];
            redI[ch * 64 + rowl] = mi[r];
        }
    }
    __syncthreads();
    if (t < BM) {
        float bv = redV[t];
        int   bi = redI[t];
        float v  = redV[64 + t];
        int   id = redI[64 + t];
        if (v < bv || (v == bv && id < bi)) { bv = v; bi = id; }
        partD[(size_t)q * NROWS + row0 + t] = bv;
        partI[(size_t)q * NROWS + row0 + t] = bi;
    }
}

// ---------------------------------------------------------------------------
// K3: merge 4 quarter-partials per row -> final index (ascending q keeps
// numpy first-min tie-breaking).
// ---------------------------------------------------------------------------
__global__ void vq_merge_kernel(const float* __restrict__ partD,
                                const int* __restrict__ partI,
                                float* __restrict__ idx_out) {
    const int row = blockIdx.x * 256 + threadIdx.x;
    float bv = partD[row];
    int   bi = partI[row];
    #pragma unroll
    for (int q = 1; q < NQ; ++q) {
        float v  = partD[(size_t)q * NROWS + row];
        int   id = partI[(size_t)q * NROWS + row];
        if (v < bv || (v == bv && id < bi)) { bv = v; bi = id; }
    }
    idx_out[row] = (float)bi;
}

// ---------------------------------------------------------------------------
// K4: gather codebook rows into quantized output (bit-exact fp32).
// ---------------------------------------------------------------------------
__global__ void vq_gather_kernel(const float* __restrict__ cb,
                                 const float* __restrict__ idx_f,
                                 float* __restrict__ quant) {
    const int t   = threadIdx.x;
    const int row = blockIdx.x * 64 + (t >> 2);
    const int seg = t & 3;
    const int best = (int)idx_f[row];
    const float4* src = (const float4*)cb + (size_t)best * (KDIM / 4);
    float4* dst = (float4*)quant + (size_t)row * (KDIM / 4);
    #pragma unroll
    for (int i = 0; i < 16; ++i)
        dst[seg * 16 + i] = src[seg * 16 + i];
}

// ---------------------------------------------------------------------------
extern "C" void kernel_launch(void* const* d_in, const int* in_sizes, int n_in,
                              void* d_out, int out_size, void* d_ws, size_t ws_size,
                              hipStream_t stream) {
    const float* z  = (const float*)d_in[0];
    const float* cb = (const float*)d_in[1];
    float* quant   = (float*)d_out;
    float* idx_out = (float*)d_out + QOUT_OFFSET;
    float* cnorm   = (float*)d_ws;                 // 32 KB scratch
    char*  cbP     = (char*)d_out;                 // 8 MB panels in quant region
    float* partD   = (float*)((char*)d_out + 8 * 1024 * 1024);   // 512 KB
    int*   partI   = (int*)((char*)d_out + 8 * 1024 * 1024 + NQ * NROWS * 4);
    // panels+partials live inside the 32 MB quant region; K4 overwrites last

    vq_panel_kernel<<<NCODES / 64, 256, 0, stream>>>(cb, cbP, cnorm);
    vq_main_kernel<<<NQ * (NROWS / BM), THREADS, 0, stream>>>(z, cbP, cnorm, partD, partI);
    vq_merge_kernel<<<NROWS / 256, 256, 0, stream>>>(partD, partI, idx_out);
    vq_gather_kernel<<<NROWS / 64, 256, 0, stream>>>(cb, idx_out, quant);
}